// Round 4
// baseline (286.017 us; speedup 1.0000x reference)
//
#include <hip/hip_runtime.h>
#include <math.h>

// (N,C,H,W) = (4,19,512,1024), f32 input, scalar f32 output.
#define NC 19
#define NN 4
#define HH 512
#define WW 1024
#define NBLK 2048            // 2048 blocks * 256 thr * 4 px = Np
#define NREP 32              // LDS accumulator replicas (rep = tid & 31)
#define COLS (2 * NC)        // 19 ssum cols + 19 hist cols

// ws layout: float partials[COLS][NBLK]; then a 4B ticket counter.
#define CNT_OFF (COLS * NBLK)

__global__ __launch_bounds__(256) void msiw_fused(
    const float* __restrict__ x, float* __restrict__ ws,
    unsigned int* __restrict__ counter, float* __restrict__ out)
{
    __shared__ float s_acc[2][NREP][NC];   // [0]=ssum, [1]=count (float, exact)
    __shared__ float s_col[COLS];
    __shared__ unsigned int s_ticket;
    const int tid = threadIdx.x;

    for (int i = tid; i < 2 * NREP * NC; i += 256) (&s_acc[0][0][0])[i] = 0.0f;
    __syncthreads();

    const int t = blockIdx.x * 256 + tid;      // 0 .. 524287
    const int w4   = t & 255;                  // W/4 = 256
    const int rest = t >> 8;
    const int h    = rest & 511;
    const int n    = rest >> 9;

    const size_t cs   = (size_t)HH * WW;                           // channel stride
    const size_t base = ((size_t)(n * NC) * HH + h) * WW + (size_t)w4 * 4;

    // Register-batched loads: all 19 float4s issued before use -> 19 loads in
    // flight per thread. This IS the latency-hiding pipeline (R3 lesson: the
    // "low-register streaming" form collapses to 1 load in flight, 4x slower).
    float vv[NC][4];
    #pragma unroll
    for (int c = 0; c < NC; ++c) {
        const float4 v = *reinterpret_cast<const float4*>(x + base + (size_t)c * cs);
        vv[c][0] = v.x; vv[c][1] = v.y; vv[c][2] = v.z; vv[c][3] = v.w;
    }

    // argmax (first occurrence via strict >)
    float m[4];
    int   pred[4];
    #pragma unroll
    for (int k = 0; k < 4; ++k) { m[k] = vv[0][k]; pred[k] = 0; }
    #pragma unroll
    for (int c = 1; c < NC; ++c) {
        #pragma unroll
        for (int k = 0; k < 4; ++k) {
            if (vv[c][k] > m[k]) { m[k] = vv[c][k]; pred[k] = c; }
        }
    }

    // Z = sum e, Q = sum e^2, e = exp(x - m);  s = Q / Z^2 = sum_j prob_j^2
    float Z[4] = {0.f, 0.f, 0.f, 0.f};
    float Q[4] = {0.f, 0.f, 0.f, 0.f};
    #pragma unroll
    for (int c = 0; c < NC; ++c) {
        #pragma unroll
        for (int k = 0; k < 4; ++k) {
            const float e = __expf(vv[c][k] - m[k]);
            Z[k] += e;
            Q[k] = fmaf(e, e, Q[k]);
        }
    }

    const int rep = tid & (NREP - 1);   // <=2-way same-address alias per wave (free)
    #pragma unroll
    for (int k = 0; k < 4; ++k) {
        const float s = Q[k] / (Z[k] * Z[k]);
        atomicAdd(&s_acc[0][rep][pred[k]], s);
        atomicAdd(&s_acc[1][rep][pred[k]], 1.0f);
    }

    __syncthreads();
    // Flush 38 per-block partials, column-major: ws[col*NBLK + block]
    if (tid < COLS) {
        const int a = (tid < NC) ? 0 : 1;
        const int c = (tid < NC) ? tid : (tid - NC);
        float acc = 0.0f;
        #pragma unroll
        for (int rp = 0; rp < NREP; ++rp) acc += s_acc[a][rp][c];
        ws[(size_t)tid * NBLK + blockIdx.x] = acc;
    }

    // Release partials at device scope; last block (by ticket) reduces.
    __threadfence();
    __syncthreads();
    if (tid == 0) s_ticket = atomicAdd(counter, 1u);
    __syncthreads();
    if (s_ticket != NBLK - 1) return;

    __threadfence();   // acquire side
    const int wv = tid >> 6, lane = tid & 63;
    for (int col = wv; col < COLS; col += 4) {
        const float* q = ws + (size_t)col * NBLK;
        float acc = 0.0f;
        #pragma unroll
        for (int i = 0; i < NBLK / 64; ++i) acc += q[lane + i * 64];
        #pragma unroll
        for (int off = 32; off > 0; off >>= 1) acc += __shfl_down(acc, off);
        if (lane == 0) s_col[col] = acc;
    }
    __syncthreads();

    if (tid == 0) {
        const double np_pow = pow((double)NN * HH * WW, 0.8);   // Np^(1-iw)
        double total = 0.0;
        for (int c = 0; c < NC; ++c) {
            double den = pow((double)s_col[NC + c], 0.2) * np_pow;
            if (den < 1.0) den = 1.0;
            total += (double)s_col[c] / den;
        }
        out[0] = (float)(-total / (double)(NN * NC));
    }
}

extern "C" void kernel_launch(void* const* d_in, const int* in_sizes, int n_in,
                              void* d_out, int out_size, void* d_ws, size_t ws_size,
                              hipStream_t stream) {
    const float* x = (const float*)d_in[0];
    float* ws = (float*)d_ws;                          // 38*2048 floats + counter
    unsigned int* counter = (unsigned int*)(ws + CNT_OFF);
    float* out = (float*)d_out;

    hipMemsetAsync(counter, 0, sizeof(unsigned int), stream);  // ticket starts at 0
    msiw_fused<<<NBLK, 256, 0, stream>>>(x, ws, counter, out);
}

// Round 5
// 57.127 us; speedup vs baseline: 5.0067x; 5.0067x over previous
//
#include <hip/hip_runtime.h>
#include <math.h>

// (N,C,H,W) = (4,19,512,1024), f32 input, scalar f32 output.
// Two-kernel structure: NO device-scope fences (R3/R4 lesson: __threadfence()
// costs ~200ns/block serialized device-wide on gfx950 -> 2048 blocks = 410us).
#define NC 19
#define NN 4
#define HH 512
#define WW 1024
#define NBLK 2048            // 2048 blocks * 256 thr * 4 px = Np
#define NREP 32              // LDS accumulator replicas (rep = tid & 31)
#define COLS (2 * NC)        // 19 ssum cols + 19 hist cols
#define CSTRIDE 2048         // column stride in ws (== NBLK)

__global__ __launch_bounds__(256) void msiw_pass1(const float* __restrict__ x,
                                                  float* __restrict__ ws) {
    __shared__ float s_acc[2][NREP][NC];   // [0]=ssum, [1]=count (float, exact)
    const int tid = threadIdx.x;

    for (int i = tid; i < 2 * NREP * NC; i += 256) (&s_acc[0][0][0])[i] = 0.0f;
    __syncthreads();

    const int t = blockIdx.x * 256 + tid;      // 0 .. 524287
    const int w4   = t & 255;                  // W/4 = 256
    const int rest = t >> 8;
    const int h    = rest & 511;
    const int n    = rest >> 9;

    const size_t cs   = (size_t)HH * WW;                           // channel stride
    const size_t base = ((size_t)(n * NC) * HH + h) * WW + (size_t)w4 * 4;

    // Register-batched loads: all 19 float4s must be ISSUED before any use.
    // The asm memory fence stops hipcc from sinking loads into the consumer
    // loops (R3/R4 showed it will otherwise collapse to a 1-deep pipeline,
    // VGPR 32-48, latency-bound). ~19 loads in flight per wave is the MLP.
    float vv[NC][4];
    #pragma unroll
    for (int c = 0; c < NC; ++c) {
        const float4 v = *reinterpret_cast<const float4*>(x + base + (size_t)c * cs);
        vv[c][0] = v.x; vv[c][1] = v.y; vv[c][2] = v.z; vv[c][3] = v.w;
    }
    asm volatile("" ::: "memory");   // no memory op sinks below this point

    // argmax (first occurrence via strict >)
    float m[4];
    int   pred[4];
    #pragma unroll
    for (int k = 0; k < 4; ++k) { m[k] = vv[0][k]; pred[k] = 0; }
    #pragma unroll
    for (int c = 1; c < NC; ++c) {
        #pragma unroll
        for (int k = 0; k < 4; ++k) {
            if (vv[c][k] > m[k]) { m[k] = vv[c][k]; pred[k] = c; }
        }
    }

    // Z = sum e, Q = sum e^2, e = exp(x - m);  s = Q / Z^2 = sum_j prob_j^2
    float Z[4] = {0.f, 0.f, 0.f, 0.f};
    float Q[4] = {0.f, 0.f, 0.f, 0.f};
    #pragma unroll
    for (int c = 0; c < NC; ++c) {
        #pragma unroll
        for (int k = 0; k < 4; ++k) {
            const float e = __expf(vv[c][k] - m[k]);
            Z[k] += e;
            Q[k] = fmaf(e, e, Q[k]);
        }
    }

    const int rep = tid & (NREP - 1);   // <=2-way same-address alias per wave (free)
    #pragma unroll
    for (int k = 0; k < 4; ++k) {
        const float s = Q[k] / (Z[k] * Z[k]);
        atomicAdd(&s_acc[0][rep][pred[k]], s);
        atomicAdd(&s_acc[1][rep][pred[k]], 1.0f);
    }

    __syncthreads();
    // Flush 38 per-block partials, column-major: ws[col*NBLK + block].
    // Kernel boundary provides the device-scope release (no fence needed).
    if (tid < COLS) {
        const int a = (tid < NC) ? 0 : 1;
        const int c = (tid < NC) ? tid : (tid - NC);
        float acc = 0.0f;
        #pragma unroll
        for (int rp = 0; rp < NREP; ++rp) acc += s_acc[a][rp][c];
        ws[(size_t)tid * CSTRIDE + blockIdx.x] = acc;
    }
}

__global__ __launch_bounds__(256) void msiw_pass2(const float* __restrict__ ws,
                                                  float* __restrict__ out) {
    __shared__ float s_col[COLS];
    const int tid  = threadIdx.x;
    const int wv   = tid >> 6;
    const int lane = tid & 63;

    for (int col = wv; col < COLS; col += 4) {
        const float* p = ws + (size_t)col * CSTRIDE;
        float acc = 0.0f;
        #pragma unroll
        for (int i = 0; i < CSTRIDE / 64; ++i) acc += p[lane + i * 64];
        #pragma unroll
        for (int off = 32; off > 0; off >>= 1) acc += __shfl_down(acc, off);
        if (lane == 0) s_col[col] = acc;
    }
    __syncthreads();

    if (tid == 0) {
        const double np_pow = pow((double)NN * HH * WW, 0.8);   // Np^(1-iw)
        double total = 0.0;
        for (int c = 0; c < NC; ++c) {
            double den = pow((double)s_col[NC + c], 0.2) * np_pow;
            if (den < 1.0) den = 1.0;
            total += (double)s_col[c] / den;
        }
        out[0] = (float)(-total / (double)(NN * NC));
    }
}

extern "C" void kernel_launch(void* const* d_in, const int* in_sizes, int n_in,
                              void* d_out, int out_size, void* d_ws, size_t ws_size,
                              hipStream_t stream) {
    const float* x = (const float*)d_in[0];
    float* ws = (float*)d_ws;                 // 38 cols * 2048 floats = 311 KB
    float* out = (float*)d_out;

    msiw_pass1<<<NBLK, 256, 0, stream>>>(x, ws);
    msiw_pass2<<<1, 256, 0, stream>>>(ws, out);
}

// Round 6
// 54.091 us; speedup vs baseline: 5.2877x; 1.0561x over previous
//
#include <hip/hip_runtime.h>
#include <math.h>

// (N,C,H,W) = (4,19,512,1024), f32 input, scalar f32 output.
// Two-kernel structure: NO device-scope fences (R3/R4 lesson: __threadfence()
// costs ~200ns/block serialized device-wide on gfx950 -> 2048 blocks = 410us).
#define NC 19
#define NN 4
#define HH 512
#define WW 1024
#define NBLK 2048            // 2048 blocks * 256 thr * 4 px = Np
#define NREP 32              // LDS accumulator replicas (rep = tid & 31)
#define COLS (2 * NC)        // 19 ssum cols + 19 hist cols
#define CSTRIDE 2048         // column stride in ws (== NBLK)

__global__ __launch_bounds__(256) void msiw_pass1(const float* __restrict__ x,
                                                  float* __restrict__ ws) {
    __shared__ float s_acc[2][NREP][NC];   // [0]=ssum, [1]=count (float, exact)
    const int tid = threadIdx.x;

    for (int i = tid; i < 2 * NREP * NC; i += 256) (&s_acc[0][0][0])[i] = 0.0f;
    __syncthreads();

    const int t = blockIdx.x * 256 + tid;      // 0 .. 524287
    const int w4   = t & 255;                  // W/4 = 256
    const int rest = t >> 8;
    const int h    = rest & 511;
    const int n    = rest >> 9;

    const size_t cs   = (size_t)HH * WW;                           // channel stride
    const size_t base = ((size_t)(n * NC) * HH + h) * WW + (size_t)w4 * 4;

    // Register-batched loads: all 19 float4s issued before any use (the batch
    // IS the latency-hiding pipeline; asm fence stops loads sinking into the
    // consumer loops).
    float vv[NC][4];
    #pragma unroll
    for (int c = 0; c < NC; ++c) {
        const float4 v = *reinterpret_cast<const float4*>(x + base + (size_t)c * cs);
        vv[c][0] = v.x; vv[c][1] = v.y; vv[c][2] = v.z; vv[c][3] = v.w;
    }
    asm volatile("" ::: "memory");

    // argmax (first occurrence via strict >)
    float m[4];
    int   pred[4];
    #pragma unroll
    for (int k = 0; k < 4; ++k) { m[k] = vv[0][k]; pred[k] = 0; }
    #pragma unroll
    for (int c = 1; c < NC; ++c) {
        #pragma unroll
        for (int k = 0; k < 4; ++k) {
            if (vv[c][k] > m[k]) { m[k] = vv[c][k]; pred[k] = c; }
        }
    }

    // Z = sum e, Q = sum e^2, e = exp(x - m);  s = Q / Z^2 = sum_j prob_j^2
    float Z[4] = {0.f, 0.f, 0.f, 0.f};
    float Q[4] = {0.f, 0.f, 0.f, 0.f};
    #pragma unroll
    for (int c = 0; c < NC; ++c) {
        #pragma unroll
        for (int k = 0; k < 4; ++k) {
            const float e = __expf(vv[c][k] - m[k]);
            Z[k] += e;
            Q[k] = fmaf(e, e, Q[k]);
        }
    }

    const int rep = tid & (NREP - 1);   // <=2-way same-address alias per wave (free)
    #pragma unroll
    for (int k = 0; k < 4; ++k) {
        const float s = Q[k] / (Z[k] * Z[k]);
        atomicAdd(&s_acc[0][rep][pred[k]], s);
        atomicAdd(&s_acc[1][rep][pred[k]], 1.0f);
    }

    __syncthreads();
    // Flush 38 per-block partials, column-major: ws[col*NBLK + block].
    // Kernel boundary provides the device-scope release (no fence needed).
    if (tid < COLS) {
        const int a = (tid < NC) ? 0 : 1;
        const int c = (tid < NC) ? tid : (tid - NC);
        float acc = 0.0f;
        #pragma unroll
        for (int rp = 0; rp < NREP; ++rp) acc += s_acc[a][rp][c];
        ws[(size_t)tid * CSTRIDE + blockIdx.x] = acc;
    }
}

// 16 waves: wave w reduces columns w, w+16, w+32 -> <=3 sequential latency
// rounds; float4 loads (8 independent 16B loads/lane/column, one batch).
__global__ __launch_bounds__(1024) void msiw_pass2(const float* __restrict__ ws,
                                                   float* __restrict__ out) {
    __shared__ float s_col[COLS];
    const int tid  = threadIdx.x;
    const int wv   = tid >> 6;       // 0..15
    const int lane = tid & 63;

    for (int col = wv; col < COLS; col += 16) {
        const float4* q = reinterpret_cast<const float4*>(ws + (size_t)col * CSTRIDE);
        float4 a[8];
        #pragma unroll
        for (int i = 0; i < 8; ++i) a[i] = q[lane + i * 64];   // 512 float4 = 2048 f
        float acc = 0.0f;
        #pragma unroll
        for (int i = 0; i < 8; ++i) acc += (a[i].x + a[i].y) + (a[i].z + a[i].w);
        #pragma unroll
        for (int off = 32; off > 0; off >>= 1) acc += __shfl_down(acc, off);
        if (lane == 0) s_col[col] = acc;
    }
    __syncthreads();

    if (tid == 0) {
        const double np_pow = pow((double)NN * HH * WW, 0.8);   // Np^(1-iw)
        double total = 0.0;
        for (int c = 0; c < NC; ++c) {
            double den = pow((double)s_col[NC + c], 0.2) * np_pow;
            if (den < 1.0) den = 1.0;
            total += (double)s_col[c] / den;
        }
        out[0] = (float)(-total / (double)(NN * NC));
    }
}

extern "C" void kernel_launch(void* const* d_in, const int* in_sizes, int n_in,
                              void* d_out, int out_size, void* d_ws, size_t ws_size,
                              hipStream_t stream) {
    const float* x = (const float*)d_in[0];
    float* ws = (float*)d_ws;                 // 38 cols * 2048 floats = 311 KB
    float* out = (float*)d_out;

    msiw_pass1<<<NBLK, 256, 0, stream>>>(x, ws);
    msiw_pass2<<<1, 1024, 0, stream>>>(ws, out);
}

// Round 8
// 53.098 us; speedup vs baseline: 5.3866x; 1.0187x over previous
//
#include <hip/hip_runtime.h>
#include <math.h>

// (N,C,H,W) = (4,19,512,1024), f32 input, scalar f32 output.
// Two-kernel structure: NO device-scope fences (R3/R4 lesson: __threadfence()
// costs ~200ns/block serialized device-wide on gfx950 -> 2048 blocks = 410us).
// R8 = R7 intent with compile fix: __builtin_nontemporal_load requires a
// native clang vector type, not HIP_vector_type (float4).
#define NC 19
#define NN 4
#define HH 512
#define WW 1024
#define NBLK 2048            // 2048 blocks * 256 thr * 4 px = Np
#define NREP 32              // LDS accumulator replicas (rep = tid & 31)
#define COLS (2 * NC)        // 19 ssum cols + 19 hist cols
#define CSTRIDE 2048         // column stride in ws (== NBLK)

typedef float floatx4 __attribute__((ext_vector_type(4)));

__global__ __launch_bounds__(256) void msiw_pass1(const float* __restrict__ x,
                                                  float* __restrict__ ws) {
    __shared__ float s_acc[2][NREP][NC];   // [0]=ssum, [1]=count (float, exact)
    const int tid = threadIdx.x;

    for (int i = tid; i < 2 * NREP * NC; i += 256) (&s_acc[0][0][0])[i] = 0.0f;
    __syncthreads();

    const int t = blockIdx.x * 256 + tid;      // 0 .. 524287
    const int w4   = t & 255;                  // W/4 = 256
    const int rest = t >> 8;
    const int h    = rest & 511;
    const int n    = rest >> 9;

    const size_t cs   = (size_t)HH * WW;                           // channel stride
    const size_t base = ((size_t)(n * NC) * HH + h) * WW + (size_t)w4 * 4;

    // Register-batched NON-TEMPORAL loads: all 19 float4s issued before any
    // use (the batch IS the latency-hiding pipeline; asm fence stops loads
    // sinking into the consumer loops).
    float vv[NC][4];
    #pragma unroll
    for (int c = 0; c < NC; ++c) {
        const floatx4* p4 = reinterpret_cast<const floatx4*>(x + base + (size_t)c * cs);
        const floatx4 v = __builtin_nontemporal_load(p4);
        vv[c][0] = v.x; vv[c][1] = v.y; vv[c][2] = v.z; vv[c][3] = v.w;
    }
    asm volatile("" ::: "memory");

    // argmax (first occurrence via strict >)
    float m[4];
    int   pred[4];
    #pragma unroll
    for (int k = 0; k < 4; ++k) { m[k] = vv[0][k]; pred[k] = 0; }
    #pragma unroll
    for (int c = 1; c < NC; ++c) {
        #pragma unroll
        for (int k = 0; k < 4; ++k) {
            if (vv[c][k] > m[k]) { m[k] = vv[c][k]; pred[k] = c; }
        }
    }

    // Z = sum e, Q = sum e^2, e = exp(x - m);  s = Q / Z^2 = sum_j prob_j^2
    float Z[4] = {0.f, 0.f, 0.f, 0.f};
    float Q[4] = {0.f, 0.f, 0.f, 0.f};
    #pragma unroll
    for (int c = 0; c < NC; ++c) {
        #pragma unroll
        for (int k = 0; k < 4; ++k) {
            const float e = __expf(vv[c][k] - m[k]);
            Z[k] += e;
            Q[k] = fmaf(e, e, Q[k]);
        }
    }

    const int rep = tid & (NREP - 1);   // <=2-way same-address alias per wave (free)
    #pragma unroll
    for (int k = 0; k < 4; ++k) {
        const float s = Q[k] / (Z[k] * Z[k]);
        atomicAdd(&s_acc[0][rep][pred[k]], s);
        atomicAdd(&s_acc[1][rep][pred[k]], 1.0f);
    }

    __syncthreads();
    // Flush 38 per-block partials, column-major: ws[col*NBLK + block].
    // Kernel boundary provides the device-scope release (no fence needed).
    // These stay cached (default) — pass2 re-reads them.
    if (tid < COLS) {
        const int a = (tid < NC) ? 0 : 1;
        const int c = (tid < NC) ? tid : (tid - NC);
        float acc = 0.0f;
        #pragma unroll
        for (int rp = 0; rp < NREP; ++rp) acc += s_acc[a][rp][c];
        ws[(size_t)tid * CSTRIDE + blockIdx.x] = acc;
    }
}

// 16 waves: wave w reduces columns w, w+16, w+32 -> <=3 sequential latency
// rounds; float4 loads (8 independent 16B loads/lane/column, one batch).
__global__ __launch_bounds__(1024) void msiw_pass2(const float* __restrict__ ws,
                                                   float* __restrict__ out) {
    __shared__ float s_col[COLS];
    const int tid  = threadIdx.x;
    const int wv   = tid >> 6;       // 0..15
    const int lane = tid & 63;

    for (int col = wv; col < COLS; col += 16) {
        const float4* q = reinterpret_cast<const float4*>(ws + (size_t)col * CSTRIDE);
        float4 a[8];
        #pragma unroll
        for (int i = 0; i < 8; ++i) a[i] = q[lane + i * 64];   // 512 float4 = 2048 f
        float acc = 0.0f;
        #pragma unroll
        for (int i = 0; i < 8; ++i) acc += (a[i].x + a[i].y) + (a[i].z + a[i].w);
        #pragma unroll
        for (int off = 32; off > 0; off >>= 1) acc += __shfl_down(acc, off);
        if (lane == 0) s_col[col] = acc;
    }
    __syncthreads();

    if (tid == 0) {
        const double np_pow = pow((double)NN * HH * WW, 0.8);   // Np^(1-iw)
        double total = 0.0;
        for (int c = 0; c < NC; ++c) {
            double den = pow((double)s_col[NC + c], 0.2) * np_pow;
            if (den < 1.0) den = 1.0;
            total += (double)s_col[c] / den;
        }
        out[0] = (float)(-total / (double)(NN * NC));
    }
}

extern "C" void kernel_launch(void* const* d_in, const int* in_sizes, int n_in,
                              void* d_out, int out_size, void* d_ws, size_t ws_size,
                              hipStream_t stream) {
    const float* x = (const float*)d_in[0];
    float* ws = (float*)d_ws;                 // 38 cols * 2048 floats = 311 KB
    float* out = (float*)d_out;

    msiw_pass1<<<NBLK, 256, 0, stream>>>(x, ws);
    msiw_pass2<<<1, 1024, 0, stream>>>(ws, out);
}